// Round 1
// baseline (601.152 us; speedup 1.0000x reference)
//
#include <hip/hip_runtime.h>
#include <stdint.h>

typedef uint16_t u16;
typedef __bf16 bf16x8 __attribute__((ext_vector_type(8)));
typedef float f32x4 __attribute__((ext_vector_type(4)));

__device__ __forceinline__ float bf2f(u16 u) {
  union { uint32_t i; float f; } v; v.i = ((uint32_t)u) << 16; return v.f;
}
__device__ __forceinline__ u16 f2bf(float f) {
  union { float f; uint32_t i; } v; v.f = f;
  uint32_t r = v.i + 0x7fffu + ((v.i >> 16) & 1u);
  return (u16)(r >> 16);
}
__device__ __forceinline__ uint32_t pack2(float a, float b) {
  return (uint32_t)f2bf(a) | ((uint32_t)f2bf(b) << 16);
}
// async global->LDS, 16B per lane; LDS dest must be wave-uniform base + lane*16
__device__ __forceinline__ void gll16(const u16* g, u16* l) {
  __builtin_amdgcn_global_load_lds((const __attribute__((address_space(1))) void*)g,
                                   (__attribute__((address_space(3))) void*)l, 16, 0, 0);
}

// ---------------- fp32 -> bf16 bulk convert ----------------
__global__ __launch_bounds__(256) void f32_to_bf16(
    const float* __restrict__ in, u16* __restrict__ out)
{
  int idx = blockIdx.x * 256 + threadIdx.x;
  float4 v = *(const float4*)(in + (size_t)idx * 4);
  uint2 o;
  o.x = pack2(v.x, v.y);
  o.y = pack2(v.z, v.w);
  *(uint2*)(out + (size_t)idx * 4) = o;
}

// ---------------- concat 3 fp32 bias vectors -> one 3072 fp32 ----------------
__global__ __launch_bounds__(256) void concat_bias(
    const float* __restrict__ a, const float* __restrict__ b,
    const float* __restrict__ c, float* __restrict__ o)
{
  int i = blockIdx.x * 256 + threadIdx.x;  // 0..3071
  float v = (i < 1024) ? a[i] : ((i < 2048) ? b[i - 1024] : c[i - 2048]);
  o[i] = v;
}

// ------- weight transpose + fp32->bf16 convert (R x C fp32 -> C x R bf16) -------
__global__ __launch_bounds__(256) void transpose_f2b(
    const float* __restrict__ in, u16* __restrict__ out, int R, int C, int ldo)
{
  __shared__ u16 tile[32][33];
  int c0 = blockIdx.x * 32, r0 = blockIdx.y * 32;
  int x = threadIdx.x, y = threadIdx.y;  // 32 x 8
#pragma unroll
  for (int i = 0; i < 32; i += 8)
    tile[y + i][x] = f2bf(in[(size_t)(r0 + y + i) * C + (c0 + x)]);
  __syncthreads();
#pragma unroll
  for (int i = 0; i < 32; i += 8)
    out[(size_t)(c0 + y + i) * ldo + (r0 + x)] = tile[x][y + i];
}

// ------- V transpose: QKV V-slice [8192][64 per head, stride 3072] ->
//         Vtg[bh][d][spos], spos = sigma(key) within each 64-key chunk,
//         sigma(key) = ((key&15)<<2) | (key>>4)  (matches flash P layout) -------
__global__ __launch_bounds__(256) void transpose_v(
    const u16* __restrict__ src, u16* __restrict__ dst)
{
  __shared__ u16 tile[64][72];
  int kc = blockIdx.x;      // key chunk (64 keys)
  int bh = blockIdx.y;      // b*16+h
  int b = bh >> 4, h = bh & 15;
  int t = threadIdx.x;
  int r = t >> 3;           // 0..31
  int c0 = (t & 7) * 8;     // 0..56
  const u16* s0 = src + ((size_t)(b * 2048 + kc * 64 + r) * 3072) + h * 64 + c0;
#pragma unroll
  for (int hh = 0; hh < 2; hh++)
    *(uint4*)(&tile[r + hh * 32][c0]) = *(const uint4*)(s0 + (size_t)hh * 32 * 3072);
  __syncthreads();
#pragma unroll
  for (int hh = 0; hh < 2; hh++) {
    int d = r + hh * 32;
    u16 vals[8];
#pragma unroll
    for (int p = 0; p < 8; p++) {
      int pos = c0 + p;
      int key = ((pos & 3) << 4) | ((pos >> 2) & 15);  // sigma^-1
      vals[p] = tile[key][d];
    }
    *(uint4*)(dst + ((size_t)bh * 64 + d) * 2048 + (size_t)kc * 64 + c0) = *(uint4*)vals;
  }
}

// ------- GEMM: C[MxN] = A[MxK(lda)] @ BT[NxK(ldb)]^T (+bias)(+C)(relu) -------
// 256x128 tile, BK=64, 512 threads (8 waves as 4m x 2n, 64x64 per wave).
// TRIPLE-buffered LDS (144 KB, 1 block/CU, 2 waves/SIMD), depth-2 prefetch:
// at tile t we issue the 6 gll16 for tile t+2, and the end-of-tile wait is a
// counted s_waitcnt vmcnt(6) (tile t+1's loads are the 6 oldest) + raw
// s_barrier. No __syncthreads in the K-loop -> no vmcnt(0) drain; each tile's
// loads have ~2 tiles of MFMA to land. XOR-block swizzle identical to the
// proven scheme: pre-swizzled global source, linear LDS dest, swizzled read.
#define GBM 256
#define GBN 128
#define GBK 64

__global__ __launch_bounds__(512, 2) void gemm_pipe(
    const u16* __restrict__ A, const u16* __restrict__ BT,
    const float* __restrict__ bias, u16* __restrict__ C,
    int N, int K, int lda, int ldb, int ldc, int relu, int addC)
{
  __shared__ __align__(16) u16 As[3][GBM * GBK];  // 3 x 32 KB
  __shared__ __align__(16) u16 Bs[3][GBN * GBK];  // 3 x 16 KB
  int tid = threadIdx.x;
  int m0 = blockIdx.y * GBM, n0 = blockIdx.x * GBN;
  int wave = tid >> 6, lane = tid & 63;
  int quad = lane >> 4, tr = lane & 15, tr7 = tr & 7;
  int wm = (wave >> 1) * 64;   // 0,64,128,192
  int wn = (wave & 1) * 64;    // 0,64

  f32x4 zero = {0.f, 0.f, 0.f, 0.f};
  f32x4 acc[4][4];
#pragma unroll
  for (int i = 0; i < 4; i++)
#pragma unroll
    for (int j = 0; j < 4; j++) acc[i][j] = zero;

  int srow = tid >> 3;                 // 0..63
  int sblk = (tid & 7) ^ (srow & 7);   // swizzled source 16B-block
  const u16* gA = A  + (size_t)(m0 + srow) * lda + sblk * 8;
  const u16* gB = BT + (size_t)(n0 + srow) * ldb + sblk * 8;
  int l8 = tid * 8;
  int NT = K >> 6;                     // >= 3 for all our shapes

  u16 *a0 = As[0], *a1 = As[1], *a2 = As[2];
  u16 *b0 = Bs[0], *b1 = Bs[1], *b2 = Bs[2];

  // ---- stage one K-tile (6 loads/thread: 4 A-rounds + 2 B-rounds) ----
#define STAGE6(la, lb)                                                \
  {                                                                   \
    _Pragma("unroll")                                                 \
    for (int R = 0; R < 4; R++)                                       \
      gll16(gA + (size_t)(R * 64) * lda, (la) + l8 + R * 4096);       \
    _Pragma("unroll")                                                 \
    for (int R = 0; R < 2; R++)                                       \
      gll16(gB + (size_t)(R * 64) * ldb, (lb) + l8 + R * 4096);       \
    gA += GBK; gB += GBK;                                             \
  }

  // prologue: tiles 0 and 1 in flight; wait for tile 0 only
  STAGE6(a0, b0);
  STAGE6(a1, b1);
  asm volatile("s_waitcnt vmcnt(6)" ::: "memory");
  __builtin_amdgcn_s_barrier();
  __builtin_amdgcn_sched_barrier(0);

  u16 *rA = a0, *nA = a1, *sA = a2;
  u16 *rB = b0, *nB = b1, *sB = b2;

  int aBase = (wm + tr) * GBK;         // u16 offset of this lane's A row
  int bBase = (wn + tr) * GBK;
  int kq0 = (quad ^ tr7) * 8;          // swizzled 16B-block, ks=0
  int kq1 = ((4 + quad) ^ tr7) * 8;    // ks=1

  for (int t = 0; t < NT; ++t) {
    if (t + 2 < NT) STAGE6(sA, sB);    // prefetch tile t+2 (buffer safe:
                                       // last read finished at end of t-1)
    bf16x8 af[4][2], bfv[4][2];
#pragma unroll
    for (int i = 0; i < 4; i++) {
      af[i][0] = *(const bf16x8*)(rA + aBase + i * 1024 + kq0);
      af[i][1] = *(const bf16x8*)(rA + aBase + i * 1024 + kq1);
    }
#pragma unroll
    for (int j = 0; j < 4; j++) {
      bfv[j][0] = *(const bf16x8*)(rB + bBase + j * 1024 + kq0);
      bfv[j][1] = *(const bf16x8*)(rB + bBase + j * 1024 + kq1);
    }
    __builtin_amdgcn_s_setprio(1);
#pragma unroll
    for (int ks = 0; ks < 2; ks++)
#pragma unroll
      for (int i = 0; i < 4; i++)
#pragma unroll
        for (int j = 0; j < 4; j++)
          acc[i][j] = __builtin_amdgcn_mfma_f32_16x16x32_bf16(
              af[i][ks], bfv[j][ks], acc[i][j], 0, 0, 0);
    __builtin_amdgcn_s_setprio(0);

    if (t + 1 < NT) {
      // tile t+1 must be fully landed; tile t+2's 6 loads may stay in flight
      if (t + 2 < NT) asm volatile("s_waitcnt vmcnt(6)" ::: "memory");
      else            asm volatile("s_waitcnt vmcnt(0)" ::: "memory");
      __builtin_amdgcn_s_barrier();
      __builtin_amdgcn_sched_barrier(0);
      u16* tp;
      tp = rA; rA = nA; nA = sA; sA = tp;
      tp = rB; rB = nB; nB = sB; sB = tp;
    }
  }
#undef STAGE6

#pragma unroll
  for (int j = 0; j < 4; j++) {
    int n = n0 + wn + j * 16 + tr;
    float bv = bias ? bias[n] : 0.f;
#pragma unroll
    for (int i = 0; i < 4; i++) {
      int mrow = m0 + wm + i * 16 + quad * 4;
#pragma unroll
      for (int r = 0; r < 4; r++) {
        size_t idx = (size_t)(mrow + r) * ldc + n;
        float v = acc[i][j][r] + bv;
        if (addC) v += bf2f(C[idx]);
        if (relu) v = v > 0.f ? v : 0.f;
        C[idx] = f2bf(v);
      }
    }
  }
}

// ---------------- flash attention v6 ----------------
// block 512 (8 waves), 32 q-rows/wave; grid (S/256, B*H).
// launch_bounds (512,4): VGPR cap 128 — round 6's (512,6) capped at 85 and
// spilled the o-accumulators to scratch (910 MB HBM write traffic, 410 µs).
// LDS is 52 KB so HW can still reach 3 blocks/CU if compiler lands <=85 VGPRs.
// K staged via gll16 into unpadded Ks[64][64] with XOR-block swizzle;
// V from pre-transposed+sigma-permuted Vtg[bh][d][key], staged the same way.
// Fixed-max softmax (scores bounded), deferred l-reduction.
__global__ __launch_bounds__(512, 4) void flash_attn(
    const u16* __restrict__ Qb, const u16* __restrict__ Kb,
    const u16* __restrict__ Vtg, u16* __restrict__ Ob, int ldqkv, int ldo)
{
  __shared__ __align__(16) u16 Ks[64][64];     // 8 KB
  __shared__ __align__(16) u16 Vt[64][64];     // 8 KB
  __shared__ __align__(16) u16 Ps[8][32][72];  // 36 KB   (total 52 KB)

  const int S = 2048;
  int tid = threadIdx.x;
  int wv = tid >> 6, lane = tid & 63;
  int quad = lane >> 4, tr = lane & 15;
  int tr7 = tr & 7;
  int bh = blockIdx.y;
  int b = bh >> 4, h = bh & 15;
  int q0 = blockIdx.x * 256;
  int wq = wv * 32;
  size_t rowbase = (size_t)b * S;
  int colbase = h * 64;

  // Q fragments: A[m=tr][k=quad*8+j]
  bf16x8 qf[2][2];
#pragma unroll
  for (int i = 0; i < 2; i++)
#pragma unroll
    for (int ks = 0; ks < 2; ks++)
      qf[i][ks] = *(const bf16x8*)(Qb + (rowbase + q0 + wq + i*16 + tr) * ldqkv
                                   + colbase + ks*32 + quad*8);

  f32x4 zero = {0.f, 0.f, 0.f, 0.f};
  f32x4 o[2][4];
  float lsum[2][4];
#pragma unroll
  for (int i = 0; i < 2; i++)
#pragma unroll
    for (int r = 0; r < 4; r++) lsum[i][r] = 0.f;
#pragma unroll
  for (int i = 0; i < 2; i++)
#pragma unroll
    for (int j = 0; j < 4; j++) o[i][j] = zero;

  const float sc = 0.125f;  // 1/sqrt(64)

  int srow = tid >> 3;                      // 0..63
  int sblk = (tid & 7) ^ (srow & 7);        // swizzled source 16B-block
  const u16* kgbase = Kb + (rowbase + srow) * ldqkv + colbase + sblk * 8;
  const u16* vgbase = Vtg + ((size_t)bh * 64 + srow) * 2048 + sblk * 8;
  u16* kl = &Ks[0][0] + tid * 8;
  u16* vl = &Vt[0][0] + tid * 8;

  for (int kv0 = 0; kv0 < S; kv0 += 64) {
    gll16(kgbase + (size_t)kv0 * ldqkv, kl);
    gll16(vgbase + kv0, vl);
    __syncthreads();

    // S = Q K^T
    f32x4 s[2][4];
#pragma unroll
    for (int i = 0; i < 2; i++)
#pragma unroll
      for (int j = 0; j < 4; j++) s[i][j] = zero;
#pragma unroll
    for (int ks = 0; ks < 2; ks++) {
      bf16x8 kf[4];
#pragma unroll
      for (int j = 0; j < 4; j++)
        kf[j] = *(const bf16x8*)(&Ks[j*16 + tr][((ks*4 + quad) ^ tr7) * 8]);
#pragma unroll
      for (int i = 0; i < 2; i++)
#pragma unroll
        for (int j = 0; j < 4; j++)
          s[i][j] = __builtin_amdgcn_mfma_f32_16x16x32_bf16(qf[i][ks], kf[j], s[i][j], 0, 0, 0);
    }

    // fixed-max softmax: p = exp(score/8); partial l per lane; P -> LDS (b64)
#pragma unroll
    for (int i = 0; i < 2; i++) {
#pragma unroll
      for (int r = 0; r < 4; r++) {
        float p0 = __expf(s[i][0][r] * sc);
        float p1 = __expf(s[i][1][r] * sc);
        float p2 = __expf(s[i][2][r] * sc);
        float p3 = __expf(s[i][3][r] * sc);
        lsum[i][r] += (p0 + p1) + (p2 + p3);
        uint2 w;
        w.x = (__float_as_uint(p0) >> 16) | (__float_as_uint(p1) & 0xffff0000u);
        w.y = (__float_as_uint(p2) >> 16) | (__float_as_uint(p3) & 0xffff0000u);
        *(uint2*)(&Ps[wv][i*16 + quad*4 + r][tr*4]) = w;
      }
    }

    // O += P @ V  (both operands in sigma-permuted key order -> consistent)
#pragma unroll
    for (int ks = 0; ks < 2; ks++) {
      bf16x8 pf[2];
#pragma unroll
      for (int i = 0; i < 2; i++)
        pf[i] = *(const bf16x8*)(&Ps[wv][i*16 + tr][ks*32 + quad*8]);
#pragma unroll
      for (int jd = 0; jd < 4; jd++) {
        bf16x8 vf = *(const bf16x8*)(&Vt[jd*16 + tr][((ks*4 + quad) ^ tr7) * 8]);
#pragma unroll
        for (int i = 0; i < 2; i++)
          o[i][jd] = __builtin_amdgcn_mfma_f32_16x16x32_bf16(pf[i], vf, o[i][jd], 0, 0, 0);
      }
    }
    __syncthreads();
  }

  // finalize: reduce l across the 16 tr lanes, scale, store
#pragma unroll
  for (int i = 0; i < 2; i++) {
#pragma unroll
    for (int r = 0; r < 4; r++) {
      float l = lsum[i][r];
      l += __shfl_xor(l, 1, 64);
      l += __shfl_xor(l, 2, 64);
      l += __shfl_xor(l, 4, 64);
      l += __shfl_xor(l, 8, 64);
      float inv = 1.f / l;
      size_t qrow = rowbase + q0 + wq + i*16 + quad*4 + r;
#pragma unroll
      for (int jd = 0; jd < 4; jd++)
        Ob[qrow * ldo + colbase + jd*16 + tr] = f2bf(o[i][jd][r] * inv);
    }
  }
}

// ---- fused residual-add + LayerNorm, variant A: X fp32 + R bf16 -> Y bf16 ----
__global__ __launch_bounds__(256) void add_ln_a(
    const float* __restrict__ X, const u16* __restrict__ Rr,
    const float* __restrict__ G, const float* __restrict__ Bb,
    u16* __restrict__ Y)
{
  int row = blockIdx.x;
  int tid = threadIdx.x;
  __shared__ float sbuf[4], qbuf[4];
  float4 xv = *(const float4*)(X + (size_t)row * 1024 + tid * 4);
  uint2 ru = *(const uint2*)(Rr + (size_t)row * 1024 + tid * 4);
  const u16* rs = (const u16*)&ru;
  const float* xs = (const float*)&xv;
  float v[4];
  float s = 0.f, q = 0.f;
#pragma unroll
  for (int e = 0; e < 4; e++) {
    float a = xs[e] + bf2f(rs[e]);
    v[e] = a; s += a; q += a * a;
  }
#pragma unroll
  for (int off = 1; off < 64; off <<= 1) {
    s += __shfl_xor(s, off, 64);
    q += __shfl_xor(q, off, 64);
  }
  if ((tid & 63) == 0) { sbuf[tid >> 6] = s; qbuf[tid >> 6] = q; }
  __syncthreads();
  s = sbuf[0] + sbuf[1] + sbuf[2] + sbuf[3];
  q = qbuf[0] + qbuf[1] + qbuf[2] + qbuf[3];
  float mu  = s * (1.f / 1024.f);
  float var = q * (1.f / 1024.f) - mu * mu;
  float inv = rsqrtf(var + 1e-5f);
#pragma unroll
  for (int e = 0; e < 4; e++) {
    int col = tid * 4 + e;
    float yv = (v[e] - mu) * inv * G[col] + Bb[col];
    Y[(size_t)row * 1024 + col] = f2bf(yv);
  }
}

// ---- variant B: X bf16 + R bf16 -> Y fp32 (final output) ----
__global__ __launch_bounds__(256) void add_ln_b(
    const u16* __restrict__ X, const u16* __restrict__ Rr,
    const float* __restrict__ G, const float* __restrict__ Bb,
    float* __restrict__ Y)
{
  int row = blockIdx.x;
  int tid = threadIdx.x;
  __shared__ float sbuf[4], qbuf[4];
  uint2 xu = *(const uint2*)(X  + (size_t)row * 1024 + tid * 4);
  uint2 ru = *(const uint2*)(Rr + (size_t)row * 1024 + tid * 4);
  const u16* xs = (const u16*)&xu;
  const u16* rs = (const u16*)&ru;
  float v[4];
  float s = 0.f, q = 0.f;
#pragma unroll
  for (int e = 0; e < 4; e++) {
    float a = bf2f(xs[e]) + bf2f(rs[e]);
    v[e] = a; s += a; q += a * a;
  }
#pragma unroll
  for (int off = 1; off < 64; off <<= 1) {
    s += __shfl_xor(s, off, 64);
    q += __shfl_xor(q, off, 64);
  }
  if ((tid & 63) == 0) { sbuf[tid >> 6] = s; qbuf[tid >> 6] = q; }
  __syncthreads();
  s = sbuf[0] + sbuf[1] + sbuf[2] + sbuf[3];
  q = qbuf[0] + qbuf[1] + qbuf[2] + qbuf[3];
  float mu  = s * (1.f / 1024.f);
  float var = q * (1.f / 1024.f) - mu * mu;
  float inv = rsqrtf(var + 1e-5f);
  float4 yv;
  float* yp = (float*)&yv;
#pragma unroll
  for (int e = 0; e < 4; e++) {
    int col = tid * 4 + e;
    yp[e] = (v[e] - mu) * inv * G[col] + Bb[col];
  }
  *(float4*)(Y + (size_t)row * 1024 + tid * 4) = yv;
}

extern "C" void kernel_launch(void* const* d_in, const int* in_sizes, int n_in,
                              void* d_out, int out_size, void* d_ws, size_t ws_size,
                              hipStream_t stream) {
  const float* x   = (const float*)d_in[0];
  const float* Wq  = (const float*)d_in[1];
  const float* bq  = (const float*)d_in[2];
  const float* Wk  = (const float*)d_in[3];
  const float* bk  = (const float*)d_in[4];
  const float* Wv  = (const float*)d_in[5];
  const float* bv  = (const float*)d_in[6];
  const float* Wo  = (const float*)d_in[7];
  const float* bo  = (const float*)d_in[8];
  const float* W1  = (const float*)d_in[9];
  const float* b1  = (const float*)d_in[10];
  const float* W2  = (const float*)d_in[11];
  const float* b2  = (const float*)d_in[12];
  const float* g1  = (const float*)d_in[13];
  const float* be1 = (const float*)d_in[14];
  const float* g2  = (const float*)d_in[15];
  const float* be2 = (const float*)d_in[16];
  float* out = (float*)d_out;
  u16* ws  = (u16*)d_ws;

  const int Nrow = 8192, E = 1024, FFd = 4096;
  const size_t M1 = 1048576;
  // workspace (44M u16 = 88 MB peak, proven safe):
  //  [0,8M):   xb -> (after QKV gemm) Vtg -> (after flash) X1
  //  [8,11M):  WqkvT [3072][1024]
  //  [11,12M): WoT
  //  [12,16M): W1T [4096][1024]
  //  [16,20M): W2T [1024][4096]
  //  [20,44M): QKV [8192][3072]; V-slice becomes ctx; region reused as F2
  // d_out (32 MB) doubles as scratch: bqkv fp32 -> AO (u16) -> Hc (u16) -> final fp32
  u16* xb     = ws;
  u16* WqkvT  = ws + 8  * M1;
  u16* WoT    = ws + 11 * M1;
  u16* W1T    = ws + 12 * M1;
  u16* W2T    = ws + 16 * M1;
  u16* QKV    = ws + 20 * M1;
  u16* Vtg    = ws;               // over xb (dead after QKV gemm)
  u16* X1     = ws;               // over Vtg (dead after flash)
  u16* F2     = ws + 20 * M1;     // over QKV (dead after Wo gemm)
  float* bqkv = (float*)d_out;
  u16*  AO    = (u16*)d_out;
  u16*  Hc    = (u16*)d_out;

  dim3 tb(256);
  dim3 tt(32, 8);
  dim3 gb(512);
  f32_to_bf16<<<dim3(8192), tb, 0, stream>>>(x, xb);
  transpose_f2b<<<dim3(E/32,  E/32),  tt, 0, stream>>>(Wq, WqkvT,        E,   E,   E);
  transpose_f2b<<<dim3(E/32,  E/32),  tt, 0, stream>>>(Wk, WqkvT + 1*M1, E,   E,   E);
  transpose_f2b<<<dim3(E/32,  E/32),  tt, 0, stream>>>(Wv, WqkvT + 2*M1, E,   E,   E);
  transpose_f2b<<<dim3(E/32,  E/32),  tt, 0, stream>>>(Wo, WoT,          E,   E,   E);
  transpose_f2b<<<dim3(FFd/32,E/32),  tt, 0, stream>>>(W1, W1T,          E,   FFd, E);
  transpose_f2b<<<dim3(E/32,  FFd/32),tt, 0, stream>>>(W2, W2T,          FFd, E,   FFd);
  concat_bias<<<dim3(12), tb, 0, stream>>>(bq, bk, bv, bqkv);

  // fused QKV projection: [8192,1024] @ [1024,3072] -> QKV
  gemm_pipe<<<dim3(3072/GBN, Nrow/GBM), gb, 0, stream>>>(xb, WqkvT, bqkv, QKV,
                                                         3072, E, E, E, 3072, 0, 0);
  // V -> Vtg (transposed + sigma-permuted, per bh)
  transpose_v<<<dim3(32, 64), tb, 0, stream>>>(QKV + 2048, Vtg);
  // flash: ctx written over the V-slice of QKV
  flash_attn<<<dim3(8, 64), dim3(512), 0, stream>>>(QKV, QKV + 1024, Vtg,
                                                    QKV + 2048, 3072, 3072);
  // Wo: ctx (stride 3072) @ WoT -> AO (in d_out)
  gemm_pipe<<<dim3(E/GBN, Nrow/GBM), gb, 0, stream>>>(QKV + 2048, WoT, bo, AO,
                                                      E, E, 3072, E, E, 0, 0);
  add_ln_a<<<dim3(Nrow), tb, 0, stream>>>(x, AO, g1, be1, X1);

  // FFN in 2 chunks of 2048 (hidden lives in d_out; F2 accumulates in ws)
  for (int c = 0; c < 2; c++) {
    gemm_pipe<<<dim3(2048/GBN, Nrow/GBM), gb, 0, stream>>>(
        X1, W1T + (size_t)c * 2048 * E, b1 + c * 2048, Hc,
        2048, E, E, E, 2048, 1, 0);
    gemm_pipe<<<dim3(E/GBN, Nrow/GBM), gb, 0, stream>>>(
        Hc, W2T + (size_t)c * 2048, (c == 0 ? b2 : (const float*)nullptr), F2,
        E, 2048, 2048, FFd, E, 0, (c == 0 ? 0 : 1));
  }

  add_ln_b<<<dim3(Nrow), tb, 0, stream>>>(X1, F2, g2, be2, out);
}

// Round 2
// 599.786 us; speedup vs baseline: 1.0023x; 1.0023x over previous
//
#include <hip/hip_runtime.h>
#include <stdint.h>

typedef uint16_t u16;
typedef __bf16 bf16x8 __attribute__((ext_vector_type(8)));
typedef float f32x4 __attribute__((ext_vector_type(4)));

__device__ __forceinline__ float bf2f(u16 u) {
  union { uint32_t i; float f; } v; v.i = ((uint32_t)u) << 16; return v.f;
}
__device__ __forceinline__ u16 f2bf(float f) {
  union { float f; uint32_t i; } v; v.f = f;
  uint32_t r = v.i + 0x7fffu + ((v.i >> 16) & 1u);
  return (u16)(r >> 16);
}
__device__ __forceinline__ uint32_t pack2(float a, float b) {
  return (uint32_t)f2bf(a) | ((uint32_t)f2bf(b) << 16);
}
// async global->LDS, 16B per lane; LDS dest must be wave-uniform base + lane*16
__device__ __forceinline__ void gll16(const u16* g, u16* l) {
  __builtin_amdgcn_global_load_lds((const __attribute__((address_space(1))) void*)g,
                                   (__attribute__((address_space(3))) void*)l, 16, 0, 0);
}

// ---------------- fp32 -> bf16 bulk convert ----------------
__global__ __launch_bounds__(256) void f32_to_bf16(
    const float* __restrict__ in, u16* __restrict__ out)
{
  int idx = blockIdx.x * 256 + threadIdx.x;
  float4 v = *(const float4*)(in + (size_t)idx * 4);
  uint2 o;
  o.x = pack2(v.x, v.y);
  o.y = pack2(v.z, v.w);
  *(uint2*)(out + (size_t)idx * 4) = o;
}

// ---------------- concat 3 fp32 bias vectors -> one 3072 fp32 ----------------
__global__ __launch_bounds__(256) void concat_bias(
    const float* __restrict__ a, const float* __restrict__ b,
    const float* __restrict__ c, float* __restrict__ o)
{
  int i = blockIdx.x * 256 + threadIdx.x;  // 0..3071
  float v = (i < 1024) ? a[i] : ((i < 2048) ? b[i - 1024] : c[i - 2048]);
  o[i] = v;
}

// ------- weight transpose + fp32->bf16 convert (R x C fp32 -> C x R bf16) -------
__global__ __launch_bounds__(256) void transpose_f2b(
    const float* __restrict__ in, u16* __restrict__ out, int R, int C, int ldo)
{
  __shared__ u16 tile[32][33];
  int c0 = blockIdx.x * 32, r0 = blockIdx.y * 32;
  int x = threadIdx.x, y = threadIdx.y;  // 32 x 8
#pragma unroll
  for (int i = 0; i < 32; i += 8)
    tile[y + i][x] = f2bf(in[(size_t)(r0 + y + i) * C + (c0 + x)]);
  __syncthreads();
#pragma unroll
  for (int i = 0; i < 32; i += 8)
    out[(size_t)(c0 + y + i) * ldo + (r0 + x)] = tile[x][y + i];
}

// ------- V transpose: QKV V-slice [8192][64 per head, stride 3072] ->
//         Vtg[bh][d][spos], spos = sigma(key) within each 64-key chunk,
//         sigma(key) = ((key&15)<<2) | (key>>4)  (matches flash P layout) -------
__global__ __launch_bounds__(256) void transpose_v(
    const u16* __restrict__ src, u16* __restrict__ dst)
{
  __shared__ u16 tile[64][72];
  int kc = blockIdx.x;      // key chunk (64 keys)
  int bh = blockIdx.y;      // b*16+h
  int b = bh >> 4, h = bh & 15;
  int t = threadIdx.x;
  int r = t >> 3;           // 0..31
  int c0 = (t & 7) * 8;     // 0..56
  const u16* s0 = src + ((size_t)(b * 2048 + kc * 64 + r) * 3072) + h * 64 + c0;
#pragma unroll
  for (int hh = 0; hh < 2; hh++)
    *(uint4*)(&tile[r + hh * 32][c0]) = *(const uint4*)(s0 + (size_t)hh * 32 * 3072);
  __syncthreads();
#pragma unroll
  for (int hh = 0; hh < 2; hh++) {
    int d = r + hh * 32;
    u16 vals[8];
#pragma unroll
    for (int p = 0; p < 8; p++) {
      int pos = c0 + p;
      int key = ((pos & 3) << 4) | ((pos >> 2) & 15);  // sigma^-1
      vals[p] = tile[key][d];
    }
    *(uint4*)(dst + ((size_t)bh * 64 + d) * 2048 + (size_t)kc * 64 + c0) = *(uint4*)vals;
  }
}

// ======================= 8-phase GEMM (m201-style port) =======================
// C[M x 256-col-tile] = A[MxK(lda)] @ BT[NxK(ldb)]^T (+bias)(+C)(relu)
// 512 threads = 8 waves as 2(M) x 4(N); per-wave output (MFR*16) x 64.
// MFR=8 -> BM=256 (LDS 128 KB), MFR=4 -> BM=128 (LDS 96 KB). BN=256, BK=64.
// Double-buffered by K-tile parity: buf0=even tiles, buf1=odd tiles.
// 8 phases per iteration (2 K-tiles); each phase: {ds-read one operand subtile,
// issue one half-tile stage, barrier, lgkmcnt(0), setprio(1), QUAD MFMAs,
// setprio(0), barrier}. Counted vmcnt gates ONLY at phases 4 and 8.
//
// Stage order (derived for safety, regions dead at issue, landed before read):
//   ph1: buf1.A h0 (tile 2i+1)   [read ph5/ph7 this iter; gated ph4]
//   ph2: buf1.A h1 (tile 2i+1)
//   ph3: buf0.B h0 (tile 2i+2)   [buf0.B reads done end ph2]
//   ph4: buf0.B h1; gate vmcnt(4) = keep ph3,ph4 halves in flight (2x2 loads)
//   ph5: buf0.A h0 (tile 2i+2)   [buf0.A reads done end ph3]
//   ph6: buf0.A h1
//   ph7: buf1.B h0 (tile 2i+3)   [buf1.B reads done end ph6]
//   ph8: buf1.B h1; gate vmcnt(4) = keep ph7,ph8 halves in flight
// Final iteration: ph3-8 stages skipped, ph4 gate becomes vmcnt(0) (else the
// ph1/ph2 A-halves would still be outstanding when ph5/ph7 read them).
// Same per-row XOR-block swizzle as proven: LDS row r block b holds global
// block b^(r&7); read side XORs with tr&7.

#define BAR  __builtin_amdgcn_s_barrier()
#define LGKM0 asm volatile("s_waitcnt lgkmcnt(0)" ::: "memory")
#define SB0  __builtin_amdgcn_sched_barrier(0)

template<int MFR>
__global__ __launch_bounds__(512, 2) void gemm8p(
    const u16* __restrict__ A, const u16* __restrict__ BT,
    const float* __restrict__ bias, u16* __restrict__ C,
    int K, int lda, int ldb, int ldc, int relu, int addC)
{
  constexpr int BM  = MFR * 32;   // 256 or 128
  constexpr int MF2 = MFR / 2;    // m-frags per sub-half: 4 or 2
  constexpr int GA  = BM / 64;    // A staging row-groups: 4 or 2
  __shared__ __align__(16) u16 As[2][BM * 64];
  __shared__ __align__(16) u16 Bs[2][256 * 64];

  int tid = threadIdx.x;
  int m0 = blockIdx.y * BM, n0 = blockIdx.x * 256;
  int wave = tid >> 6, lane = tid & 63;
  int quad = lane >> 4, tr = lane & 15, tr7 = tr & 7;
  int wm = (wave >> 2) * (BM / 2);   // 0 or BM/2
  int wn = (wave & 3) * 64;          // 0,64,128,192

  f32x4 zero = {0.f, 0.f, 0.f, 0.f};
  f32x4 acc[MFR][4];
#pragma unroll
  for (int f = 0; f < MFR; f++)
#pragma unroll
    for (int j = 0; j < 4; j++) acc[f][j] = zero;

  int srow = tid >> 3;                 // 0..63
  int sblk = (tid & 7) ^ (srow & 7);   // swizzled source 16B-block
  const u16* gAs = A  + (size_t)(m0 + srow) * lda + sblk * 8;
  const u16* gBs = BT + (size_t)(n0 + srow) * ldb + sblk * 8;
  u16* lA0 = &As[0][0] + tid * 8;
  u16* lA1 = &As[1][0] + tid * 8;
  u16* lB0 = &Bs[0][0] + tid * 8;
  u16* lB1 = &Bs[1][0] + tid * 8;

  int aRow = (wm + tr) * 64;           // u16 index; frag f adds f*1024
  int bRow = (wn + tr) * 64;
  int kq0 = (quad ^ tr7) * 8;          // swizzled 16B-block, ks=0
  int kq1 = ((4 + quad) ^ tr7) * 8;    // ks=1

  int NT = K >> 6, NI = NT >> 1;       // K multiple of 128 in all our shapes

  // stage A half h of tile T into lbuf (GA/2 gll16 per thread)
#define STG_A(lbuf, h, T)                                                   \
  { _Pragma("unroll")                                                       \
    for (int g = (h) * (GA / 2); g < ((h) + 1) * (GA / 2); ++g)             \
      gll16(gAs + (size_t)(T) * 64 + (size_t)(g * 64) * lda,                \
            (lbuf) + g * 4096); }
  // stage B half h of tile T (2 gll16 per thread)
#define STG_B(lbuf, h, T)                                                   \
  { _Pragma("unroll")                                                       \
    for (int g = 2 * (h); g < 2 * (h) + 2; ++g)                             \
      gll16(gBs + (size_t)(T) * 64 + (size_t)(g * 64) * ldb,                \
            (lbuf) + g * 4096); }
#define LD_A(buf, sub)                                                      \
  { _Pragma("unroll")                                                       \
    for (int f = 0; f < MF2; ++f) {                                         \
      aq[f][0] = *(const bf16x8*)(&As[buf][aRow + ((sub) * MF2 + f) * 1024 + kq0]); \
      aq[f][1] = *(const bf16x8*)(&As[buf][aRow + ((sub) * MF2 + f) * 1024 + kq1]); \
    } }
#define LD_B(buf, sub, dst)                                                 \
  { _Pragma("unroll")                                                       \
    for (int j = 0; j < 2; ++j) {                                           \
      dst[j][0] = *(const bf16x8*)(&Bs[buf][bRow + ((sub) * 2 + j) * 1024 + kq0]); \
      dst[j][1] = *(const bf16x8*)(&Bs[buf][bRow + ((sub) * 2 + j) * 1024 + kq1]); \
    } }
#define QUAD(msub, nsub, bsrc)                                              \
  { _Pragma("unroll")                                                       \
    for (int ks = 0; ks < 2; ++ks)                                          \
      _Pragma("unroll")                                                     \
      for (int f = 0; f < MF2; ++f)                                         \
        _Pragma("unroll")                                                   \
        for (int j = 0; j < 2; ++j)                                         \
          acc[(msub) * MF2 + f][(nsub) * 2 + j] =                           \
              __builtin_amdgcn_mfma_f32_16x16x32_bf16(                      \
                  aq[f][ks], bsrc[j][ks],                                   \
                  acc[(msub) * MF2 + f][(nsub) * 2 + j], 0, 0, 0); }

  // prologue: tile0 (A+B) and tile1 (B only; tile1's A staged at iter0 ph1-2)
  STG_A(lA0, 0, 0); STG_A(lA0, 1, 0);
  STG_B(lB0, 0, 0); STG_B(lB0, 1, 0);
  STG_B(lB1, 0, 1); STG_B(lB1, 1, 1);
  asm volatile("s_waitcnt vmcnt(0)" ::: "memory");
  BAR;

  bf16x8 aq[MF2][2], bq0[2][2], bq1[2][2];

  for (int i = 0; i < NI; ++i) {
    int tb = 2 * i + 1, t2 = 2 * i + 2, t3 = 2 * i + 3;
    bool more = (t2 < NT);             // uniform across block
    // ---- ph1: read buf0 A sub0 + B sub0; stage buf1.A h0; Q(0,0)
    LD_A(0, 0); LD_B(0, 0, bq0);
    STG_A(lA1, 0, tb);
    BAR; LGKM0; SB0;
    __builtin_amdgcn_s_setprio(1); QUAD(0, 0, bq0); __builtin_amdgcn_s_setprio(0);
    BAR;
    // ---- ph2: read buf0 B sub1; stage buf1.A h1; Q(0,1)
    LD_B(0, 1, bq1);
    STG_A(lA1, 1, tb);
    BAR; LGKM0; SB0;
    __builtin_amdgcn_s_setprio(1); QUAD(0, 1, bq1); __builtin_amdgcn_s_setprio(0);
    BAR;
    // ---- ph3: read buf0 A sub1; stage buf0.B h0; Q(1,1)
    LD_A(0, 1);
    if (more) STG_B(lB0, 0, t2);
    BAR; LGKM0; SB0;
    __builtin_amdgcn_s_setprio(1); QUAD(1, 1, bq1); __builtin_amdgcn_s_setprio(0);
    BAR;
    // ---- ph4: stage buf0.B h1; Q(1,0); vmcnt gate
    if (more) STG_B(lB0, 1, t2);
    BAR;
    __builtin_amdgcn_s_setprio(1); QUAD(1, 0, bq0); __builtin_amdgcn_s_setprio(0);
    if (more) { asm volatile("s_waitcnt vmcnt(4)" ::: "memory"); }
    else      { asm volatile("s_waitcnt vmcnt(0)" ::: "memory"); }
    BAR;
    // ---- ph5: read buf1 A sub0 + B sub0; stage buf0.A h0; Q(0,0)
    LD_A(1, 0); LD_B(1, 0, bq0);
    if (more) STG_A(lA0, 0, t2);
    BAR; LGKM0; SB0;
    __builtin_amdgcn_s_setprio(1); QUAD(0, 0, bq0); __builtin_amdgcn_s_setprio(0);
    BAR;
    // ---- ph6: read buf1 B sub1; stage buf0.A h1; Q(0,1)
    LD_B(1, 1, bq1);
    if (more) STG_A(lA0, 1, t2);
    BAR; LGKM0; SB0;
    __builtin_amdgcn_s_setprio(1); QUAD(0, 1, bq1); __builtin_amdgcn_s_setprio(0);
    BAR;
    // ---- ph7: read buf1 A sub1; stage buf1.B h0; Q(1,1)
    LD_A(1, 1);
    if (more) STG_B(lB1, 0, t3);
    BAR; LGKM0; SB0;
    __builtin_amdgcn_s_setprio(1); QUAD(1, 1, bq1); __builtin_amdgcn_s_setprio(0);
    BAR;
    // ---- ph8: stage buf1.B h1; Q(1,0); vmcnt gate
    if (more) STG_B(lB1, 1, t3);
    BAR;
    __builtin_amdgcn_s_setprio(1); QUAD(1, 0, bq0); __builtin_amdgcn_s_setprio(0);
    if (more) { asm volatile("s_waitcnt vmcnt(4)" ::: "memory"); }
    BAR;
  }
#undef STG_A
#undef STG_B
#undef LD_A
#undef LD_B
#undef QUAD

  // epilogue
#pragma unroll
  for (int j = 0; j < 4; j++) {
    int n = n0 + wn + j * 16 + tr;
    float bv = bias ? bias[n] : 0.f;
#pragma unroll
    for (int f = 0; f < MFR; f++) {
      int mrow = m0 + wm + f * 16 + quad * 4;
#pragma unroll
      for (int r = 0; r < 4; r++) {
        size_t idx = (size_t)(mrow + r) * ldc + n;
        float v = acc[f][j][r] + bv;
        if (addC) v += bf2f(C[idx]);
        if (relu) v = v > 0.f ? v : 0.f;
        C[idx] = f2bf(v);
      }
    }
  }
}

// ---------------- flash attention v6 ----------------
// block 512 (8 waves), 32 q-rows/wave; grid (S/256, B*H).
// launch_bounds (512,4): VGPR cap 128 — round 6's (512,6) capped at 85 and
// spilled the o-accumulators to scratch (910 MB HBM write traffic, 410 µs).
// LDS is 52 KB so HW can still reach 3 blocks/CU if compiler lands <=85 VGPRs.
// K staged via gll16 into unpadded Ks[64][64] with XOR-block swizzle;
// V from pre-transposed+sigma-permuted Vtg[bh][d][key], staged the same way.
// Fixed-max softmax (scores bounded), deferred l-reduction.
__global__ __launch_bounds__(512, 4) void flash_attn(
    const u16* __restrict__ Qb, const u16* __restrict__ Kb,
    const u16* __restrict__ Vtg, u16* __restrict__ Ob, int ldqkv, int ldo)
{
  __shared__ __align__(16) u16 Ks[64][64];     // 8 KB
  __shared__ __align__(16) u16 Vt[64][64];     // 8 KB
  __shared__ __align__(16) u16 Ps[8][32][72];  // 36 KB   (total 52 KB)

  const int S = 2048;
  int tid = threadIdx.x;
  int wv = tid >> 6, lane = tid & 63;
  int quad = lane >> 4, tr = lane & 15;
  int tr7 = tr & 7;
  int bh = blockIdx.y;
  int b = bh >> 4, h = bh & 15;
  int q0 = blockIdx.x * 256;
  int wq = wv * 32;
  size_t rowbase = (size_t)b * S;
  int colbase = h * 64;

  // Q fragments: A[m=tr][k=quad*8+j]
  bf16x8 qf[2][2];
#pragma unroll
  for (int i = 0; i < 2; i++)
#pragma unroll
    for (int ks = 0; ks < 2; ks++)
      qf[i][ks] = *(const bf16x8*)(Qb + (rowbase + q0 + wq + i*16 + tr) * ldqkv
                                   + colbase + ks*32 + quad*8);

  f32x4 zero = {0.f, 0.f, 0.f, 0.f};
  f32x4 o[2][4];
  float lsum[2][4];
#pragma unroll
  for (int i = 0; i < 2; i++)
#pragma unroll
    for (int r = 0; r < 4; r++) lsum[i][r] = 0.f;
#pragma unroll
  for (int i = 0; i < 2; i++)
#pragma unroll
    for (int j = 0; j < 4; j++) o[i][j] = zero;

  const float sc = 0.125f;  // 1/sqrt(64)

  int srow = tid >> 3;                      // 0..63
  int sblk = (tid & 7) ^ (srow & 7);        // swizzled source 16B-block
  const u16* kgbase = Kb + (rowbase + srow) * ldqkv + colbase + sblk * 8;
  const u16* vgbase = Vtg + ((size_t)bh * 64 + srow) * 2048 + sblk * 8;
  u16* kl = &Ks[0][0] + tid * 8;
  u16* vl = &Vt[0][0] + tid * 8;

  for (int kv0 = 0; kv0 < S; kv0 += 64) {
    gll16(kgbase + (size_t)kv0 * ldqkv, kl);
    gll16(vgbase + kv0, vl);
    __syncthreads();

    // S = Q K^T
    f32x4 s[2][4];
#pragma unroll
    for (int i = 0; i < 2; i++)
#pragma unroll
      for (int j = 0; j < 4; j++) s[i][j] = zero;
#pragma unroll
    for (int ks = 0; ks < 2; ks++) {
      bf16x8 kf[4];
#pragma unroll
      for (int j = 0; j < 4; j++)
        kf[j] = *(const bf16x8*)(&Ks[j*16 + tr][((ks*4 + quad) ^ tr7) * 8]);
#pragma unroll
      for (int i = 0; i < 2; i++)
#pragma unroll
        for (int j = 0; j < 4; j++)
          s[i][j] = __builtin_amdgcn_mfma_f32_16x16x32_bf16(qf[i][ks], kf[j], s[i][j], 0, 0, 0);
    }

    // fixed-max softmax: p = exp(score/8); partial l per lane; P -> LDS (b64)
#pragma unroll
    for (int i = 0; i < 2; i++) {
#pragma unroll
      for (int r = 0; r < 4; r++) {
        float p0 = __expf(s[i][0][r] * sc);
        float p1 = __expf(s[i][1][r] * sc);
        float p2 = __expf(s[i][2][r] * sc);
        float p3 = __expf(s[i][3][r] * sc);
        lsum[i][r] += (p0 + p1) + (p2 + p3);
        uint2 w;
        w.x = (__float_as_uint(p0) >> 16) | (__float_as_uint(p1) & 0xffff0000u);
        w.y = (__float_as_uint(p2) >> 16) | (__float_as_uint(p3) & 0xffff0000u);
        *(uint2*)(&Ps[wv][i*16 + quad*4 + r][tr*4]) = w;
      }
    }

    // O += P @ V  (both operands in sigma-permuted key order -> consistent)
#pragma unroll
    for (int ks = 0; ks < 2; ks++) {
      bf16x8 pf[2];
#pragma unroll
      for (int i = 0; i < 2; i++)
        pf[i] = *(const bf16x8*)(&Ps[wv][i*16 + tr][ks*32 + quad*8]);
#pragma unroll
      for (int jd = 0; jd < 4; jd++) {
        bf16x8 vf = *(const bf16x8*)(&Vt[jd*16 + tr][((ks*4 + quad) ^ tr7) * 8]);
#pragma unroll
        for (int i = 0; i < 2; i++)
          o[i][jd] = __builtin_amdgcn_mfma_f32_16x16x32_bf16(pf[i], vf, o[i][jd], 0, 0, 0);
      }
    }
    __syncthreads();
  }

  // finalize: reduce l across the 16 tr lanes, scale, store
#pragma unroll
  for (int i = 0; i < 2; i++) {
#pragma unroll
    for (int r = 0; r < 4; r++) {
      float l = lsum[i][r];
      l += __shfl_xor(l, 1, 64);
      l += __shfl_xor(l, 2, 64);
      l += __shfl_xor(l, 4, 64);
      l += __shfl_xor(l, 8, 64);
      float inv = 1.f / l;
      size_t qrow = rowbase + q0 + wq + i*16 + quad*4 + r;
#pragma unroll
      for (int jd = 0; jd < 4; jd++)
        Ob[qrow * ldo + colbase + jd*16 + tr] = f2bf(o[i][jd][r] * inv);
    }
  }
}

// ---- fused residual-add + LayerNorm, variant A: X fp32 + R bf16 -> Y bf16 ----
__global__ __launch_bounds__(256) void add_ln_a(
    const float* __restrict__ X, const u16* __restrict__ Rr,
    const float* __restrict__ G, const float* __restrict__ Bb,
    u16* __restrict__ Y)
{
  int row = blockIdx.x;
  int tid = threadIdx.x;
  __shared__ float sbuf[4], qbuf[4];
  float4 xv = *(const float4*)(X + (size_t)row * 1024 + tid * 4);
  uint2 ru = *(const uint2*)(Rr + (size_t)row * 1024 + tid * 4);
  const u16* rs = (const u16*)&ru;
  const float* xs = (const float*)&xv;
  float v[4];
  float s = 0.f, q = 0.f;
#pragma unroll
  for (int e = 0; e < 4; e++) {
    float a = xs[e] + bf2f(rs[e]);
    v[e] = a; s += a; q += a * a;
  }
#pragma unroll
  for (int off = 1; off < 64; off <<= 1) {
    s += __shfl_xor(s, off, 64);
    q += __shfl_xor(q, off, 64);
  }
  if ((tid & 63) == 0) { sbuf[tid >> 6] = s; qbuf[tid >> 6] = q; }
  __syncthreads();
  s = sbuf[0] + sbuf[1] + sbuf[2] + sbuf[3];
  q = qbuf[0] + qbuf[1] + qbuf[2] + qbuf[3];
  float mu  = s * (1.f / 1024.f);
  float var = q * (1.f / 1024.f) - mu * mu;
  float inv = rsqrtf(var + 1e-5f);
#pragma unroll
  for (int e = 0; e < 4; e++) {
    int col = tid * 4 + e;
    float yv = (v[e] - mu) * inv * G[col] + Bb[col];
    Y[(size_t)row * 1024 + col] = f2bf(yv);
  }
}

// ---- variant B: X bf16 + R bf16 -> Y fp32 (final output) ----
__global__ __launch_bounds__(256) void add_ln_b(
    const u16* __restrict__ X, const u16* __restrict__ Rr,
    const float* __restrict__ G, const float* __restrict__ Bb,
    float* __restrict__ Y)
{
  int row = blockIdx.x;
  int tid = threadIdx.x;
  __shared__ float sbuf[4], qbuf[4];
  uint2 xu = *(const uint2*)(X  + (size_t)row * 1024 + tid * 4);
  uint2 ru = *(const uint2*)(Rr + (size_t)row * 1024 + tid * 4);
  const u16* xs = (const u16*)&xu;
  const u16* rs = (const u16*)&ru;
  float v[4];
  float s = 0.f, q = 0.f;
#pragma unroll
  for (int e = 0; e < 4; e++) {
    float a = bf2f(xs[e]) + bf2f(rs[e]);
    v[e] = a; s += a; q += a * a;
  }
#pragma unroll
  for (int off = 1; off < 64; off <<= 1) {
    s += __shfl_xor(s, off, 64);
    q += __shfl_xor(q, off, 64);
  }
  if ((tid & 63) == 0) { sbuf[tid >> 6] = s; qbuf[tid >> 6] = q; }
  __syncthreads();
  s = sbuf[0] + sbuf[1] + sbuf[2] + sbuf[3];
  q = qbuf[0] + qbuf[1] + qbuf[2] + qbuf[3];
  float mu  = s * (1.f / 1024.f);
  float var = q * (1.f / 1024.f) - mu * mu;
  float inv = rsqrtf(var + 1e-5f);
  float4 yv;
  float* yp = (float*)&yv;
#pragma unroll
  for (int e = 0; e < 4; e++) {
    int col = tid * 4 + e;
    yp[e] = (v[e] - mu) * inv * G[col] + Bb[col];
  }
  *(float4*)(Y + (size_t)row * 1024 + tid * 4) = yv;
}

extern "C" void kernel_launch(void* const* d_in, const int* in_sizes, int n_in,
                              void* d_out, int out_size, void* d_ws, size_t ws_size,
                              hipStream_t stream) {
  const float* x   = (const float*)d_in[0];
  const float* Wq  = (const float*)d_in[1];
  const float* bq  = (const float*)d_in[2];
  const float* Wk  = (const float*)d_in[3];
  const float* bk  = (const float*)d_in[4];
  const float* Wv  = (const float*)d_in[5];
  const float* bv  = (const float*)d_in[6];
  const float* Wo  = (const float*)d_in[7];
  const float* bo  = (const float*)d_in[8];
  const float* W1  = (const float*)d_in[9];
  const float* b1  = (const float*)d_in[10];
  const float* W2  = (const float*)d_in[11];
  const float* b2  = (const float*)d_in[12];
  const float* g1  = (const float*)d_in[13];
  const float* be1 = (const float*)d_in[14];
  const float* g2  = (const float*)d_in[15];
  const float* be2 = (const float*)d_in[16];
  float* out = (float*)d_out;
  u16* ws  = (u16*)d_ws;

  const int Nrow = 8192, E = 1024, FFd = 4096;
  const size_t M1 = 1048576;
  // workspace (44M u16 = 88 MB peak, proven safe):
  //  [0,8M):   xb -> (after QKV gemm) Vtg -> (after flash) X1
  //  [8,11M):  WqkvT [3072][1024]
  //  [11,12M): WoT
  //  [12,16M): W1T [4096][1024]
  //  [16,20M): W2T [1024][4096]
  //  [20,44M): QKV [8192][3072]; V-slice becomes ctx; region reused as F2
  // d_out (32 MB) doubles as scratch: bqkv fp32 -> AO (u16) -> Hc (u16) -> final fp32
  u16* xb     = ws;
  u16* WqkvT  = ws + 8  * M1;
  u16* WoT    = ws + 11 * M1;
  u16* W1T    = ws + 12 * M1;
  u16* W2T    = ws + 16 * M1;
  u16* QKV    = ws + 20 * M1;
  u16* Vtg    = ws;               // over xb (dead after QKV gemm)
  u16* X1     = ws;               // over Vtg (dead after flash)
  u16* F2     = ws + 20 * M1;     // over QKV (dead after Wo gemm)
  float* bqkv = (float*)d_out;
  u16*  AO    = (u16*)d_out;
  u16*  Hc    = (u16*)d_out;

  dim3 tb(256);
  dim3 tt(32, 8);
  dim3 gb(512);
  f32_to_bf16<<<dim3(8192), tb, 0, stream>>>(x, xb);
  transpose_f2b<<<dim3(E/32,  E/32),  tt, 0, stream>>>(Wq, WqkvT,        E,   E,   E);
  transpose_f2b<<<dim3(E/32,  E/32),  tt, 0, stream>>>(Wk, WqkvT + 1*M1, E,   E,   E);
  transpose_f2b<<<dim3(E/32,  E/32),  tt, 0, stream>>>(Wv, WqkvT + 2*M1, E,   E,   E);
  transpose_f2b<<<dim3(E/32,  E/32),  tt, 0, stream>>>(Wo, WoT,          E,   E,   E);
  transpose_f2b<<<dim3(FFd/32,E/32),  tt, 0, stream>>>(W1, W1T,          E,   FFd, E);
  transpose_f2b<<<dim3(E/32,  FFd/32),tt, 0, stream>>>(W2, W2T,          FFd, E,   FFd);
  concat_bias<<<dim3(12), tb, 0, stream>>>(bq, bk, bv, bqkv);

  // fused QKV projection: [8192,1024] @ [1024,3072] -> QKV  (BM=256: 12x32 blocks)
  gemm8p<8><<<dim3(3072/256, Nrow/256), gb, 0, stream>>>(xb, WqkvT, bqkv, QKV,
                                                         E, E, E, 3072, 0, 0);
  // V -> Vtg (transposed + sigma-permuted, per bh)
  transpose_v<<<dim3(32, 64), tb, 0, stream>>>(QKV + 2048, Vtg);
  // flash: ctx written over the V-slice of QKV
  flash_attn<<<dim3(8, 64), dim3(512), 0, stream>>>(QKV, QKV + 1024, Vtg,
                                                    QKV + 2048, 3072, 3072);
  // Wo: ctx (stride 3072) @ WoT -> AO (in d_out).  N=1024 -> BM=128: 4x64 blocks
  gemm8p<4><<<dim3(E/256, Nrow/128), gb, 0, stream>>>(QKV + 2048, WoT, bo, AO,
                                                      E, 3072, E, E, 0, 0);
  add_ln_a<<<dim3(Nrow), tb, 0, stream>>>(x, AO, g1, be1, X1);

  // FFN in 2 chunks of 2048 (hidden lives in d_out; F2 accumulates in ws)
  for (int c = 0; c < 2; c++) {
    gemm8p<8><<<dim3(2048/256, Nrow/256), gb, 0, stream>>>(
        X1, W1T + (size_t)c * 2048 * E, b1 + c * 2048, Hc,
        E, E, E, 2048, 1, 0);
    gemm8p<4><<<dim3(E/256, Nrow/128), gb, 0, stream>>>(
        Hc, W2T + (size_t)c * 2048, (c == 0 ? b2 : (const float*)nullptr), F2,
        2048, 2048, FFd, E, 0, (c == 0 ? 0 : 1));
  }

  add_ln_b<<<dim3(Nrow), tb, 0, stream>>>(X1, F2, g2, be2, out);
}

// Round 3
// 533.497 us; speedup vs baseline: 1.1268x; 1.1243x over previous
//
#include <hip/hip_runtime.h>
#include <stdint.h>

typedef uint16_t u16;
typedef __bf16 bf16x8 __attribute__((ext_vector_type(8)));
typedef float f32x4 __attribute__((ext_vector_type(4)));

__device__ __forceinline__ float bf2f(u16 u) {
  union { uint32_t i; float f; } v; v.i = ((uint32_t)u) << 16; return v.f;
}
__device__ __forceinline__ u16 f2bf(float f) {
  union { float f; uint32_t i; } v; v.f = f;
  uint32_t r = v.i + 0x7fffu + ((v.i >> 16) & 1u);
  return (u16)(r >> 16);
}
__device__ __forceinline__ uint32_t pack2(float a, float b) {
  return (uint32_t)f2bf(a) | ((uint32_t)f2bf(b) << 16);
}
// async global->LDS, 16B per lane; LDS dest must be wave-uniform base + lane*16
__device__ __forceinline__ void gll16(const u16* g, u16* l) {
  __builtin_amdgcn_global_load_lds((const __attribute__((address_space(1))) void*)g,
                                   (__attribute__((address_space(3))) void*)l, 16, 0, 0);
}

// ---------------- fp32 -> bf16 bulk convert ----------------
__global__ __launch_bounds__(256) void f32_to_bf16(
    const float* __restrict__ in, u16* __restrict__ out)
{
  int idx = blockIdx.x * 256 + threadIdx.x;
  float4 v = *(const float4*)(in + (size_t)idx * 4);
  uint2 o;
  o.x = pack2(v.x, v.y);
  o.y = pack2(v.z, v.w);
  *(uint2*)(out + (size_t)idx * 4) = o;
}

// ---------------- concat 3 fp32 bias vectors -> one 3072 fp32 ----------------
__global__ __launch_bounds__(256) void concat_bias(
    const float* __restrict__ a, const float* __restrict__ b,
    const float* __restrict__ c, float* __restrict__ o)
{
  int i = blockIdx.x * 256 + threadIdx.x;  // 0..3071
  float v = (i < 1024) ? a[i] : ((i < 2048) ? b[i - 1024] : c[i - 2048]);
  o[i] = v;
}

// ------- weight transpose + fp32->bf16 convert (R x C fp32 -> C x R bf16) -------
__global__ __launch_bounds__(256) void transpose_f2b(
    const float* __restrict__ in, u16* __restrict__ out, int R, int C, int ldo)
{
  __shared__ u16 tile[32][33];
  int c0 = blockIdx.x * 32, r0 = blockIdx.y * 32;
  int x = threadIdx.x, y = threadIdx.y;  // 32 x 8
#pragma unroll
  for (int i = 0; i < 32; i += 8)
    tile[y + i][x] = f2bf(in[(size_t)(r0 + y + i) * C + (c0 + x)]);
  __syncthreads();
#pragma unroll
  for (int i = 0; i < 32; i += 8)
    out[(size_t)(c0 + y + i) * ldo + (r0 + x)] = tile[x][y + i];
}

// ------- V transpose: QKV V-slice [8192][64 per head, stride 3072] ->
//         Vtg[bh][d][spos], spos = sigma(key) within each 64-key chunk,
//         sigma(key) = ((key&15)<<2) | (key>>4)  (matches flash P layout) -------
__global__ __launch_bounds__(256) void transpose_v(
    const u16* __restrict__ src, u16* __restrict__ dst)
{
  __shared__ u16 tile[64][72];
  int kc = blockIdx.x;      // key chunk (64 keys)
  int bh = blockIdx.y;      // b*16+h
  int b = bh >> 4, h = bh & 15;
  int t = threadIdx.x;
  int r = t >> 3;           // 0..31
  int c0 = (t & 7) * 8;     // 0..56
  const u16* s0 = src + ((size_t)(b * 2048 + kc * 64 + r) * 3072) + h * 64 + c0;
#pragma unroll
  for (int hh = 0; hh < 2; hh++)
    *(uint4*)(&tile[r + hh * 32][c0]) = *(const uint4*)(s0 + (size_t)hh * 32 * 3072);
  __syncthreads();
#pragma unroll
  for (int hh = 0; hh < 2; hh++) {
    int d = r + hh * 32;
    u16 vals[8];
#pragma unroll
    for (int p = 0; p < 8; p++) {
      int pos = c0 + p;
      int key = ((pos & 3) << 4) | ((pos >> 2) & 15);  // sigma^-1
      vals[p] = tile[key][d];
    }
    *(uint4*)(dst + ((size_t)bh * 64 + d) * 2048 + (size_t)kc * 64 + c0) = *(uint4*)vals;
  }
}

// ------- GEMM: C[MxN] = A[MxK(lda)] @ BT[NxK(ldb)]^T (+bias)(+C)(relu) -------
// BK=64, async gll16 staging with XOR-block swizzle:
//   physical 16B-block b' = b ^ (row & 7); applied on global source address.
// NOTE (rounds 0/1): 512-thread big-LDS restructures (triple-buffer coarse
// pipeline; faithful m201 8-phase) BOTH regressed ~66 us at these shapes
// (K=1024-2048, small grids). Occupancy (3 blocks/CU) + fine compiler
// scheduling beat the deep pipelines here. Keep this structure.
// Round 2: XCD-chunked block swizzle (all grids %8==0 -> bijective): each XCD
// gets a contiguous (by, bx-sweep) range so A-panels stay L2-resident.
#define BM 128
#define BN 128
#define BK 64

__global__ __launch_bounds__(256, 2) void gemm_bt(
    const u16* __restrict__ A, const u16* __restrict__ BT,
    const float* __restrict__ bias, u16* __restrict__ C,
    int N, int K, int lda, int ldb, int ldc, int relu, int addC)
{
  __shared__ __align__(16) u16 As[BM][BK];   // 16 KB
  __shared__ __align__(16) u16 Bs[BN][BK];   // 16 KB
  int tid = threadIdx.x;
  // XCD-chunked swizzle: id%8 = XCD (HW round-robin); give each XCD a
  // contiguous nid chunk (row-major over (by,bx) -> bx sweeps fastest,
  // A-panel reused gridDim.x times within an XCD's L2).
  int gx = gridDim.x;
  int id = blockIdx.y * gx + blockIdx.x;
  int cpx = (gx * gridDim.y) >> 3;
  int nid = (id & 7) * cpx + (id >> 3);
  int m0 = (nid / gx) * BM, n0 = (nid % gx) * BN;
  int wave = tid >> 6, lane = tid & 63;
  int quad = lane >> 4, tr = lane & 15;
  int wm = (wave >> 1) * 64, wn = (wave & 1) * 64;
  int tr7 = tr & 7;

  f32x4 zero = {0.f, 0.f, 0.f, 0.f};
  f32x4 acc[4][4];
#pragma unroll
  for (int i = 0; i < 4; i++)
#pragma unroll
    for (int j = 0; j < 4; j++) acc[i][j] = zero;

  int srow = tid >> 3;                      // 0..31
  int sblk = (tid & 7) ^ (srow & 7);        // swizzled source 16B-block
  const u16* Abase = A  + (size_t)(m0 + srow) * lda + sblk * 8;
  const u16* Bbase = BT + (size_t)(n0 + srow) * ldb + sblk * 8;
  u16* la = &As[0][0] + tid * 8;
  u16* lb = &Bs[0][0] + tid * 8;

  for (int k0 = 0; k0 < K; k0 += BK) {
#pragma unroll
    for (int R = 0; R < 4; R++) {
      gll16(Abase + (size_t)(R * 32) * lda + k0, la + R * 2048);
      gll16(Bbase + (size_t)(R * 32) * ldb + k0, lb + R * 2048);
    }
    __syncthreads();
#pragma unroll
    for (int ks = 0; ks < 2; ks++) {
      bf16x8 af[4], bfr[4];
#pragma unroll
      for (int i = 0; i < 4; i++)
        af[i]  = *(const bf16x8*)(&As[wm + i*16 + tr][(((ks*4 + quad) ^ tr7)) * 8]);
#pragma unroll
      for (int j = 0; j < 4; j++)
        bfr[j] = *(const bf16x8*)(&Bs[wn + j*16 + tr][(((ks*4 + quad) ^ tr7)) * 8]);
#pragma unroll
      for (int i = 0; i < 4; i++)
#pragma unroll
        for (int j = 0; j < 4; j++)
          acc[i][j] = __builtin_amdgcn_mfma_f32_16x16x32_bf16(af[i], bfr[j], acc[i][j], 0, 0, 0);
    }
    __syncthreads();
  }

#pragma unroll
  for (int j = 0; j < 4; j++) {
    int n = n0 + wn + j*16 + tr;
    float bv = bias ? bias[n] : 0.f;
#pragma unroll
    for (int i = 0; i < 4; i++) {
      int mrow = m0 + wm + i*16 + quad*4;
#pragma unroll
      for (int r = 0; r < 4; r++) {
        size_t idx = (size_t)(mrow + r) * ldc + n;
        float v = acc[i][j][r] + bv;
        if (addC) v += bf2f(C[idx]);
        if (relu) v = v > 0.f ? v : 0.f;
        C[idx] = f2bf(v);
      }
    }
  }
}

// ---------------- flash attention v6 + XCD swizzle ----------------
// block 512 (8 waves), 32 q-rows/wave; grid (S/256, B*H).
// launch_bounds (512,4): VGPR cap 128.
// Round 2: XCD swizzle — all 8 q-chunks of one bh map to the same XCD
// (64 blocks/XCD = 8 bh x 8 q-chunks; 8 x 512KB K/V = 4MB = one L2), so the
// per-iteration vmcnt(0)-drained K/V loads hit L2 instead of LLC/HBM.
// Observed pre-swizzle: FETCH_SIZE 139MB vs 48MB unique inputs (~3x L2-miss).
__global__ __launch_bounds__(512, 4) void flash_attn(
    const u16* __restrict__ Qb, const u16* __restrict__ Kb,
    const u16* __restrict__ Vtg, u16* __restrict__ Ob, int ldqkv, int ldo)
{
  __shared__ __align__(16) u16 Ks[64][64];     // 8 KB
  __shared__ __align__(16) u16 Vt[64][64];     // 8 KB
  __shared__ __align__(16) u16 Ps[8][32][72];  // 36 KB   (total 52 KB)

  const int S = 2048;
  int tid = threadIdx.x;
  int wv = tid >> 6, lane = tid & 63;
  int quad = lane >> 4, tr = lane & 15;
  int tr7 = tr & 7;
  // XCD swizzle: linear id -> (xcd = id%8, s = id/8); bh = xcd*8 + s%8,
  // q-chunk = s/8. Bijective on the 8x64 grid; same-bh blocks share id%8.
  int id = blockIdx.y * 8 + blockIdx.x;        // gridDim.x == 8
  int xcd = id & 7, sidx = id >> 3;
  int bh = xcd * 8 + (sidx & 7);
  int q0 = (sidx >> 3) * 256;
  int b = bh >> 4, h = bh & 15;
  int wq = wv * 32;
  size_t rowbase = (size_t)b * S;
  int colbase = h * 64;

  // Q fragments: A[m=tr][k=quad*8+j]
  bf16x8 qf[2][2];
#pragma unroll
  for (int i = 0; i < 2; i++)
#pragma unroll
    for (int ks = 0; ks < 2; ks++)
      qf[i][ks] = *(const bf16x8*)(Qb + (rowbase + q0 + wq + i*16 + tr) * ldqkv
                                   + colbase + ks*32 + quad*8);

  f32x4 zero = {0.f, 0.f, 0.f, 0.f};
  f32x4 o[2][4];
  float lsum[2][4];
#pragma unroll
  for (int i = 0; i < 2; i++)
#pragma unroll
    for (int r = 0; r < 4; r++) lsum[i][r] = 0.f;
#pragma unroll
  for (int i = 0; i < 2; i++)
#pragma unroll
    for (int j = 0; j < 4; j++) o[i][j] = zero;

  const float sc = 0.125f;  // 1/sqrt(64)

  int srow = tid >> 3;                      // 0..63
  int sblk = (tid & 7) ^ (srow & 7);        // swizzled source 16B-block
  const u16* kgbase = Kb + (rowbase + srow) * ldqkv + colbase + sblk * 8;
  const u16* vgbase = Vtg + ((size_t)bh * 64 + srow) * 2048 + sblk * 8;
  u16* kl = &Ks[0][0] + tid * 8;
  u16* vl = &Vt[0][0] + tid * 8;

  for (int kv0 = 0; kv0 < S; kv0 += 64) {
    gll16(kgbase + (size_t)kv0 * ldqkv, kl);
    gll16(vgbase + kv0, vl);
    __syncthreads();

    // S = Q K^T
    f32x4 s[2][4];
#pragma unroll
    for (int i = 0; i < 2; i++)
#pragma unroll
      for (int j = 0; j < 4; j++) s[i][j] = zero;
#pragma unroll
    for (int ks = 0; ks < 2; ks++) {
      bf16x8 kf[4];
#pragma unroll
      for (int j = 0; j < 4; j++)
        kf[j] = *(const bf16x8*)(&Ks[j*16 + tr][((ks*4 + quad) ^ tr7) * 8]);
#pragma unroll
      for (int i = 0; i < 2; i++)
#pragma unroll
        for (int j = 0; j < 4; j++)
          s[i][j] = __builtin_amdgcn_mfma_f32_16x16x32_bf16(qf[i][ks], kf[j], s[i][j], 0, 0, 0);
    }

    // fixed-max softmax: p = exp(score/8); partial l per lane; P -> LDS (b64)
#pragma unroll
    for (int i = 0; i < 2; i++) {
#pragma unroll
      for (int r = 0; r < 4; r++) {
        float p0 = __expf(s[i][0][r] * sc);
        float p1 = __expf(s[i][1][r] * sc);
        float p2 = __expf(s[i][2][r] * sc);
        float p3 = __expf(s[i][3][r] * sc);
        lsum[i][r] += (p0 + p1) + (p2 + p3);
        uint2 w;
        w.x = (__float_as_uint(p0) >> 16) | (__float_as_uint(p1) & 0xffff0000u);
        w.y = (__float_as_uint(p2) >> 16) | (__float_as_uint(p3) & 0xffff0000u);
        *(uint2*)(&Ps[wv][i*16 + quad*4 + r][tr*4]) = w;
      }
    }

    // O += P @ V  (both operands in sigma-permuted key order -> consistent)
#pragma unroll
    for (int ks = 0; ks < 2; ks++) {
      bf16x8 pf[2];
#pragma unroll
      for (int i = 0; i < 2; i++)
        pf[i] = *(const bf16x8*)(&Ps[wv][i*16 + tr][ks*32 + quad*8]);
#pragma unroll
      for (int jd = 0; jd < 4; jd++) {
        bf16x8 vf = *(const bf16x8*)(&Vt[jd*16 + tr][((ks*4 + quad) ^ tr7) * 8]);
#pragma unroll
        for (int i = 0; i < 2; i++)
          o[i][jd] = __builtin_amdgcn_mfma_f32_16x16x32_bf16(pf[i], vf, o[i][jd], 0, 0, 0);
      }
    }
    __syncthreads();
  }

  // finalize: reduce l across the 16 tr lanes, scale, store
#pragma unroll
  for (int i = 0; i < 2; i++) {
#pragma unroll
    for (int r = 0; r < 4; r++) {
      float l = lsum[i][r];
      l += __shfl_xor(l, 1, 64);
      l += __shfl_xor(l, 2, 64);
      l += __shfl_xor(l, 4, 64);
      l += __shfl_xor(l, 8, 64);
      float inv = 1.f / l;
      size_t qrow = rowbase + q0 + wq + i*16 + quad*4 + r;
#pragma unroll
      for (int jd = 0; jd < 4; jd++)
        Ob[qrow * ldo + colbase + jd*16 + tr] = f2bf(o[i][jd][r] * inv);
    }
  }
}

// ---- fused residual-add + LayerNorm, variant A: X fp32 + R bf16 -> Y bf16 ----
__global__ __launch_bounds__(256) void add_ln_a(
    const float* __restrict__ X, const u16* __restrict__ Rr,
    const float* __restrict__ G, const float* __restrict__ Bb,
    u16* __restrict__ Y)
{
  int row = blockIdx.x;
  int tid = threadIdx.x;
  __shared__ float sbuf[4], qbuf[4];
  float4 xv = *(const float4*)(X + (size_t)row * 1024 + tid * 4);
  uint2 ru = *(const uint2*)(Rr + (size_t)row * 1024 + tid * 4);
  const u16* rs = (const u16*)&ru;
  const float* xs = (const float*)&xv;
  float v[4];
  float s = 0.f, q = 0.f;
#pragma unroll
  for (int e = 0; e < 4; e++) {
    float a = xs[e] + bf2f(rs[e]);
    v[e] = a; s += a; q += a * a;
  }
#pragma unroll
  for (int off = 1; off < 64; off <<= 1) {
    s += __shfl_xor(s, off, 64);
    q += __shfl_xor(q, off, 64);
  }
  if ((tid & 63) == 0) { sbuf[tid >> 6] = s; qbuf[tid >> 6] = q; }
  __syncthreads();
  s = sbuf[0] + sbuf[1] + sbuf[2] + sbuf[3];
  q = qbuf[0] + qbuf[1] + qbuf[2] + qbuf[3];
  float mu  = s * (1.f / 1024.f);
  float var = q * (1.f / 1024.f) - mu * mu;
  float inv = rsqrtf(var + 1e-5f);
#pragma unroll
  for (int e = 0; e < 4; e++) {
    int col = tid * 4 + e;
    float yv = (v[e] - mu) * inv * G[col] + Bb[col];
    Y[(size_t)row * 1024 + col] = f2bf(yv);
  }
}

// ---- variant B: X bf16 + R bf16 -> Y fp32 (final output) ----
__global__ __launch_bounds__(256) void add_ln_b(
    const u16* __restrict__ X, const u16* __restrict__ Rr,
    const float* __restrict__ G, const float* __restrict__ Bb,
    float* __restrict__ Y)
{
  int row = blockIdx.x;
  int tid = threadIdx.x;
  __shared__ float sbuf[4], qbuf[4];
  uint2 xu = *(const uint2*)(X  + (size_t)row * 1024 + tid * 4);
  uint2 ru = *(const uint2*)(Rr + (size_t)row * 1024 + tid * 4);
  const u16* xs = (const u16*)&xu;
  const u16* rs = (const u16*)&ru;
  float v[4];
  float s = 0.f, q = 0.f;
#pragma unroll
  for (int e = 0; e < 4; e++) {
    float a = bf2f(xs[e]) + bf2f(rs[e]);
    v[e] = a; s += a; q += a * a;
  }
#pragma unroll
  for (int off = 1; off < 64; off <<= 1) {
    s += __shfl_xor(s, off, 64);
    q += __shfl_xor(q, off, 64);
  }
  if ((tid & 63) == 0) { sbuf[tid >> 6] = s; qbuf[tid >> 6] = q; }
  __syncthreads();
  s = sbuf[0] + sbuf[1] + sbuf[2] + sbuf[3];
  q = qbuf[0] + qbuf[1] + qbuf[2] + qbuf[3];
  float mu  = s * (1.f / 1024.f);
  float var = q * (1.f / 1024.f) - mu * mu;
  float inv = rsqrtf(var + 1e-5f);
  float4 yv;
  float* yp = (float*)&yv;
#pragma unroll
  for (int e = 0; e < 4; e++) {
    int col = tid * 4 + e;
    yp[e] = (v[e] - mu) * inv * G[col] + Bb[col];
  }
  *(float4*)(Y + (size_t)row * 1024 + tid * 4) = yv;
}

extern "C" void kernel_launch(void* const* d_in, const int* in_sizes, int n_in,
                              void* d_out, int out_size, void* d_ws, size_t ws_size,
                              hipStream_t stream) {
  const float* x   = (const float*)d_in[0];
  const float* Wq  = (const float*)d_in[1];
  const float* bq  = (const float*)d_in[2];
  const float* Wk  = (const float*)d_in[3];
  const float* bk  = (const float*)d_in[4];
  const float* Wv  = (const float*)d_in[5];
  const float* bv  = (const float*)d_in[6];
  const float* Wo  = (const float*)d_in[7];
  const float* bo  = (const float*)d_in[8];
  const float* W1  = (const float*)d_in[9];
  const float* b1  = (const float*)d_in[10];
  const float* W2  = (const float*)d_in[11];
  const float* b2  = (const float*)d_in[12];
  const float* g1  = (const float*)d_in[13];
  const float* be1 = (const float*)d_in[14];
  const float* g2  = (const float*)d_in[15];
  const float* be2 = (const float*)d_in[16];
  float* out = (float*)d_out;
  u16* ws  = (u16*)d_ws;

  const int Nrow = 8192, E = 1024, FFd = 4096;
  const size_t M1 = 1048576;
  // workspace (44M u16 = 88 MB peak, proven safe):
  //  [0,8M):   xb -> (after QKV gemm) Vtg -> (after flash) X1
  //  [8,11M):  WqkvT [3072][1024]
  //  [11,12M): WoT
  //  [12,16M): W1T [4096][1024]
  //  [16,20M): W2T [1024][4096]
  //  [20,44M): QKV [8192][3072]; V-slice becomes ctx; region reused as F2
  // d_out (32 MB) doubles as scratch: bqkv fp32 -> AO (u16) -> Hc (u16) -> final fp32
  u16* xb     = ws;
  u16* WqkvT  = ws + 8  * M1;
  u16* WoT    = ws + 11 * M1;
  u16* W1T    = ws + 12 * M1;
  u16* W2T    = ws + 16 * M1;
  u16* QKV    = ws + 20 * M1;
  u16* Vtg    = ws;               // over xb (dead after QKV gemm)
  u16* X1     = ws;               // over Vtg (dead after flash)
  u16* F2     = ws + 20 * M1;     // over QKV (dead after Wo gemm)
  float* bqkv = (float*)d_out;
  u16*  AO    = (u16*)d_out;
  u16*  Hc    = (u16*)d_out;

  dim3 tb(256);
  dim3 tt(32, 8);
  f32_to_bf16<<<dim3(8192), tb, 0, stream>>>(x, xb);
  transpose_f2b<<<dim3(E/32,  E/32),  tt, 0, stream>>>(Wq, WqkvT,        E,   E,   E);
  transpose_f2b<<<dim3(E/32,  E/32),  tt, 0, stream>>>(Wk, WqkvT + 1*M1, E,   E,   E);
  transpose_f2b<<<dim3(E/32,  E/32),  tt, 0, stream>>>(Wv, WqkvT + 2*M1, E,   E,   E);
  transpose_f2b<<<dim3(E/32,  E/32),  tt, 0, stream>>>(Wo, WoT,          E,   E,   E);
  transpose_f2b<<<dim3(FFd/32,E/32),  tt, 0, stream>>>(W1, W1T,          E,   FFd, E);
  transpose_f2b<<<dim3(E/32,  FFd/32),tt, 0, stream>>>(W2, W2T,          FFd, E,   FFd);
  concat_bias<<<dim3(12), tb, 0, stream>>>(bq, bk, bv, bqkv);

  // fused QKV projection: [8192,1024] @ [1024,3072] -> QKV
  gemm_bt<<<dim3(24, Nrow/BM), tb, 0, stream>>>(xb, WqkvT, bqkv, QKV,
                                                3072, E, E, E, 3072, 0, 0);
  // V -> Vtg (transposed + sigma-permuted, per bh)
  transpose_v<<<dim3(32, 64), tb, 0, stream>>>(QKV + 2048, Vtg);
  // flash: ctx written over the V-slice of QKV
  flash_attn<<<dim3(8, 64), dim3(512), 0, stream>>>(QKV, QKV + 1024, Vtg,
                                                    QKV + 2048, 3072, 3072);
  // Wo: ctx (stride 3072) @ WoT -> AO (in d_out)
  gemm_bt<<<dim3(8, Nrow/BM), tb, 0, stream>>>(QKV + 2048, WoT, bo, AO,
                                               E, E, 3072, E, E, 0, 0);
  add_ln_a<<<dim3(Nrow), tb, 0, stream>>>(x, AO, g1, be1, X1);

  // FFN in 2 chunks of 2048 (hidden lives in d_out; F2 accumulates in ws)
  for (int c = 0; c < 2; c++) {
    gemm_bt<<<dim3(16, Nrow/BM), tb, 0, stream>>>(
        X1, W1T + (size_t)c * 2048 * E, b1 + c * 2048, Hc,
        2048, E, E, E, 2048, 1, 0);
    gemm_bt<<<dim3(8, Nrow/BM), tb, 0, stream>>>(
        Hc, W2T + (size_t)c * 2048, (c == 0 ? b2 : (const float*)nullptr), F2,
        E, 2048, 2048, FFd, E, 0, (c == 0 ? 0 : 1));
  }

  add_ln_b<<<dim3(Nrow), tb, 0, stream>>>(X1, F2, g2, be2, out);
}